// Round 12
// baseline (111.599 us; speedup 1.0000x reference)
//
#include <hip/hip_runtime.h>
#include <hip/hip_bf16.h>

// Conv2d 3x3 s1 p1, NCHW: X(32,128,56,56) f32 * W(256,128,3,3) f32 -> out(32,256,56,56) f32
// R12: (a) M-group=1 blocks 64oc x 448px, 4 waves 1Mx4N -> total LDS B-reads HALVE;
//      (b) plane-split window layout [4 ic-octet planes][10 rows][58 cols][16B],
//          plane stride 9312B -> 16-lane frag reads are 256B contiguous = conflict-free,
//          swz() deleted (staging linear, reads linear: both-sides-or-neither);
//      (c) tap body: B ds_reads first, A-prefetch second, MFMA third.
// Kept from R10 (68us, passing): A L2->VGPR dbuf by global tap parity, window dbuf
// with ONE vmcnt(0)+barrier+sched_barrier per ic-slice, staging at end of tap 4,
// XCD-swizzled grid. LDS 75776B -> 2 blocks/CU co-resident.

#define IC 128
#define OC 256
#define HH 56
#define WW 56
#define NB 32
#define PH 58
#define PW 58
#define PS (PH*PW)
#define NPIX (HH*WW)      // 3136
#define GPIX (NB*NPIX)    // 100352
#define KDIM (IC*9)       // 1152

#define BNP 448           // pixels per block (8 rows x 56)
#define PLSTR 9312        // plane stride bytes (9280 content + 32 pad; banks 0,24,16,8)
#define WINB 37888        // buffer bytes: 2368 slots of 16B (2328 content + slack)

typedef short  bf16x8 __attribute__((ext_vector_type(8)));
typedef float  f32x4  __attribute__((ext_vector_type(4)));
typedef unsigned int u32;

__device__ __forceinline__ unsigned short f2bf(float f) {
  union { float f; unsigned int u; } c; c.f = f;
  unsigned int u = c.u;
  u += 0x7FFFu + ((u >> 16) & 1u);
  return (unsigned short)(u >> 16);
}

__device__ __forceinline__ void gload16(const unsigned short* g, unsigned short* l) {
  __builtin_amdgcn_global_load_lds(
      (const __attribute__((address_space(1))) u32*)g,
      (__attribute__((address_space(3))) u32*)l, 16, 0, 0);
}

// ---- prepass 1a: zero padded border of Xt
__global__ __launch_bounds__(256) void zero_border(unsigned short* __restrict__ Xt, int total) {
  int idx = blockIdx.x * 256 + threadIdx.x;
  if (idx >= total) return;
  int e  = idx & 127;
  int b  = idx >> 7;
  int n  = b / 228;
  int bp = b - n * 228;
  int y, x;
  if (bp < 58)       { y = 0;  x = bp; }
  else if (bp < 116) { y = 57; x = bp - 58; }
  else {
    int b2 = bp - 116;
    y = 1 + (b2 >> 1);
    x = (b2 & 1) * 57;
  }
  Xt[((long)(n * PH + y) * PW + x) * IC + e] = 0;
}

// ---- prepass 1b: NCHW f32 -> NHWC-padded bf16 (LDS-tiled transpose)
__global__ __launch_bounds__(256) void pad_x_nhwc(const float* __restrict__ X,
                                                  unsigned short* __restrict__ Xt) {
  __shared__ float tile[128][65];
  const int t   = threadIdx.x;
  const int p0  = blockIdx.x * 64;
  const int n   = p0 / NPIX;
  const int rem = p0 - n * NPIX;

  const int pixl = t & 63;
  const int q    = t >> 6;
  const float* src = X + ((long)n * IC + q) * NPIX + rem + pixl;
  #pragma unroll
  for (int i = 0; i < 32; ++i)
    tile[q + i * 4][pixl] = src[(long)i * 4 * NPIX];
  __syncthreads();

  const int pix = t >> 2;
  const int icq = (t & 3) * 32;
  int p = rem + pix;
  int y = p / WW, x = p - y * WW;
  unsigned short* dst = Xt + ((long)(n * PH + y + 1) * PW + (x + 1)) * IC + icq;
  #pragma unroll
  for (int g = 0; g < 4; ++g) {
    bf16x8 v;
    #pragma unroll
    for (int j = 0; j < 8; ++j)
      ((unsigned short*)&v)[j] = f2bf(tile[icq + g * 8 + j][pix]);
    *reinterpret_cast<bf16x8*>(dst + g * 8) = v;
  }
}

// ---- prepass 2: W (OIHW f32) -> Wb bf16 [tap][ic_octet s][oc][8 ic]
__global__ __launch_bounds__(256) void pack_w(const float* __restrict__ W,
                                              unsigned short* __restrict__ Wb, int total) {
  int idx = blockIdx.x * 256 + threadIdx.x;
  if (idx >= total) return;
  int e  = idx & 7;
  int oc = (idx >> 3) & 255;
  int s  = (idx >> 11) & 15;
  int t  = idx >> 15;
  Wb[idx] = f2bf(W[(oc * IC + s * 8 + e) * 9 + t]);
}

// ---- main: halo-window implicit GEMM, 64oc x 448px blocks, plane-split window
__global__ __launch_bounds__(256) void conv_win(
    const unsigned short* __restrict__ Xt,
    const unsigned short* __restrict__ Wb,
    float* __restrict__ out) {
  __shared__ __align__(16) unsigned short lds[37888];   // 75776 B: 2 window buffers
  char* const ldsb = (char*)lds;

  const int tid  = threadIdx.x;
  const int lane = tid & 63;
  const int w    = tid >> 6;             // 4 waves, 1M x 4N; wave tile 64oc x 112px
  const int wn   = w;
  const int l15 = lane & 15, lh = lane >> 4;

  // XCD-aware bijective remap: 896 = 8 x 112; adjacent wg share a pixel tile
  const int bid = blockIdx.x;
  const int wg  = (bid & 7) * 112 + (bid >> 3);
  const int pt  = wg >> 2;               // pixel-tile 0..223
  const int ocb = (wg & 3) * 64;
  const int n   = pt / 7;
  const int rg  = pt - n * 7;
  const int y0  = rg * 8;                // padded top row of window

  // ---- A source: per-lane VGPR loads, coalesced (16 lanes x 16B contiguous)
  const unsigned short* aBase = Wb + (size_t)lh * 2048 + (ocb + l15) * 8;

  // ---- window staging sources (10 slots/thread; content = 4 planes x [10][58][16B])
  const unsigned short* srcW[10];
  #pragma unroll
  for (int r = 0; r < 10; ++r) {
    int slot = (r < 9) ? (r * 256 + tid) : (2304 + lane);   // call 9: wave 0 only
    int x = slot * 16;
    int plane = x / PLSTR; if (plane > 3) plane = 3;
    int rem = x - plane * PLSTR; if (rem >= 9280) rem = 9264;  // pad/slack: dup
    int pix = rem >> 4;
    int row = pix / 58, col = pix - row * 58;
    srcW[r] = Xt + ((long)((n * PH + y0 + row) * PW + col)) * IC + plane * 8;
  }

  // ---- fragment linear offsets (plane-split: lh = ic octet plane)
  int pixLin[7];
  #pragma unroll
  for (int j = 0; j < 7; ++j) {
    int local = wn * 112 + j * 16 + l15;     // 0..447 within block
    int wy = local / 56, wx = local - wy * 56;
    pixLin[j] = lh * PLSTR + (wy * 58 + wx) * 16;
  }

  f32x4 acc[4][7];
  #pragma unroll
  for (int m = 0; m < 4; ++m)
    #pragma unroll
    for (int j = 0; j < 7; ++j)
      acc[m][j] = (f32x4){0.f, 0.f, 0.f, 0.f};

  auto stageWin = [&](int icb) {          // slice icb -> buf (icb&1); wave-uniform dest
    char* base = ldsb + (icb & 1) * WINB + (tid & ~63) * 16;
    #pragma unroll
    for (int r = 0; r < 10; ++r)
      if (r < 9 || w == 0)
        gload16(srcW[r] + icb * 32, (unsigned short*)(base + r * 4096));
  };

  // ---- prologue
  stageWin(0);
  bf16x8 aReg[2][4];
  #pragma unroll
  for (int m = 0; m < 4; ++m)
    aReg[0][m] = *(const bf16x8*)(aBase + m * 128);        // A(q=0): tap0, icb0
  asm volatile("s_waitcnt vmcnt(0)" ::: "memory");
  __builtin_amdgcn_s_barrier();
  __builtin_amdgcn_sched_barrier(0);

  for (int icb = 0; icb < 4; ++icb) {
    const int winSel = (icb & 1) * WINB;

    #pragma unroll
    for (int tap = 0; tap < 9; ++tap) {
      // global tap parity: q = icb*9+tap ; 9 odd => q&1 == (icb+tap)&1
      const int rs = (icb + tap) & 1;          // read slot
      const int ps = rs ^ 1;                   // prefetch slot (q+1)

      const int dy = tap / 3, dx = tap - dy * 3;   // compile-time (tap unrolled)
      const int toff = (dy * 58 + dx) * 16;

      // (1) B ds_reads first: lgkm latency drains under the A-issue VALU work
      bf16x8 bfv[7];
      #pragma unroll
      for (int j = 0; j < 7; ++j)
        bfv[j] = *(const bf16x8*)(ldsb + winSel + pixLin[j] + toff);

      // (2) prefetch A for q+1 (never collides: ps != rs)
      if (tap < 8) {
        #pragma unroll
        for (int m = 0; m < 4; ++m)
          aReg[ps][m] = *(const bf16x8*)(aBase + (size_t)(tap + 1) * 32768
                                               + (size_t)icb * 8192 + m * 128);
      } else if (icb < 3) {
        #pragma unroll
        for (int m = 0; m < 4; ++m)
          aReg[ps][m] = *(const bf16x8*)(aBase + (size_t)(icb + 1) * 8192 + m * 128);
      }

      // (3) MFMA burst
      __builtin_amdgcn_s_setprio(1);
      #pragma unroll
      for (int j = 0; j < 7; ++j)
        #pragma unroll
        for (int m = 0; m < 4; ++m)
          acc[m][j] = __builtin_amdgcn_mfma_f32_16x16x32_bf16(aReg[rs][m], bfv[j],
                                                              acc[m][j], 0, 0, 0);
      __builtin_amdgcn_s_setprio(0);

      // staging after tap 4: A-prefetch waits at taps<=5 don't force-retire staging
      if (tap == 4 && icb < 3) stageWin(icb + 1);
    }

    // window(icb+1) fully staged (all waves) before reading it; WAR on buf icb&1
    // certified for the stage at icb+2 by this same barrier.
    asm volatile("s_waitcnt vmcnt(0)" ::: "memory");
    __builtin_amdgcn_s_barrier();
    __builtin_amdgcn_sched_barrier(0);
  }

  // ---- epilogue: D row=(lane>>4)*4+reg (oc), col=lane&15 (pixel)
  #pragma unroll
  for (int j = 0; j < 7; ++j) {
    int pidx = rg * BNP + wn * 112 + j * 16 + l15;   // pixel within image
    #pragma unroll
    for (int m = 0; m < 4; ++m) {
      int oc = ocb + m * 16 + lh * 4;
      float* op = out + ((long)(n * OC + oc)) * NPIX + pidx;
      #pragma unroll
      for (int r = 0; r < 4; ++r)
        op[(long)r * NPIX] = acc[m][j][r];
    }
  }
}

// ---- fallback: naive direct conv fp32
__global__ __launch_bounds__(256) void conv_naive(const float* __restrict__ X,
                                                  const float* __restrict__ W,
                                                  float* __restrict__ out, int total) {
  int idx = blockIdx.x * 256 + threadIdx.x;
  if (idx >= total) return;
  int prow = idx % NPIX;
  int t    = idx / NPIX;
  int oc   = t % OC;
  int n    = t / OC;
  int oh = prow / WW, ow = prow % WW;
  float s = 0.f;
  for (int ic = 0; ic < IC; ++ic) {
    const float* xp = X + ((long)(n * IC + ic)) * NPIX;
    const float* wp = W + ((long)(oc * IC + ic)) * 9;
    #pragma unroll
    for (int kh = 0; kh < 3; ++kh) {
      int ih = oh + kh - 1;
      if (ih < 0 || ih >= HH) continue;
      #pragma unroll
      for (int kw = 0; kw < 3; ++kw) {
        int iw = ow + kw - 1;
        if (iw < 0 || iw >= WW) continue;
        s += xp[ih * WW + iw] * wp[kh * 3 + kw];
      }
    }
  }
  out[idx] = s;
}

extern "C" void kernel_launch(void* const* d_in, const int* in_sizes, int n_in,
                              void* d_out, int out_size, void* d_ws, size_t ws_size,
                              hipStream_t stream) {
  const float* X = (const float*)d_in[0];
  const float* W = (const float*)d_in[1];
  float* out = (float*)d_out;

  const size_t xt_elems = (size_t)NB * PS * IC;
  const size_t wb_elems = (size_t)9 * 16 * 256 * 8;   // 294,912
  const size_t need = (xt_elems + wb_elems) * sizeof(unsigned short);

  if (ws_size >= need) {
    unsigned short* Xt = (unsigned short*)d_ws;
    unsigned short* Wb = Xt + xt_elems;

    int totB = NB * 228 * IC;
    zero_border<<<(totB + 255) / 256, 256, 0, stream>>>(Xt, totB);
    pad_x_nhwc<<<GPIX / 64, 256, 0, stream>>>(X, Xt);
    int totW = (int)wb_elems;
    pack_w<<<(totW + 255) / 256, 256, 0, stream>>>(W, Wb, totW);
    conv_win<<<(GPIX / BNP) * 4, 256, 0, stream>>>(Xt, Wb, out);
  } else {
    int tot = NB * OC * NPIX;
    conv_naive<<<(tot + 255) / 256, 256, 0, stream>>>(X, W, out, tot);
  }
}

// Round 13
// 102.963 us; speedup vs baseline: 1.0839x; 1.0839x over previous
//
#include <hip/hip_runtime.h>
#include <hip/hip_bf16.h>

// Conv2d 3x3 s1 p1, NCHW: X(32,128,56,56) f32 * W(256,128,3,3) f32 -> out(32,256,56,56) f32
// R13: mfma_32x32x16 + depth-1 software pipeline over 18 k-steps/slice.
// Wave = 128oc (4 M-tiles) x 64px (2 N-tiles): acc[4][2] f32x16 =128r, aReg[2][4]=32r,
// bfv[2][2]=16r -> ~230 regs, 2 waves/SIMD WITH pipelining (R9's spill fixed by K=16
// B-frags). Block = 7 N-waves (448 thr) = 128oc x 448px; grid 448 (=R10). B-LDS traffic
// halves vs R10 (pixel read by 1 wave). Window = 4 ic-octet planes [580px][16B]
// (PLSTR 9280B): 32-lane frag reads 512B contiguous = conflict-free, no swizzle.
// Pipeline slot parity = kh (= ks&1; 18 even => consistent across slices).
// Sync: ONE vmcnt(0)+s_barrier+sched_barrier per ic-slice (proven R7/R8/R10).

#define IC 128
#define OC 256
#define HH 56
#define WW 56
#define NB 32
#define PH 58
#define PW 58
#define PS (PH*PW)
#define NPIX (HH*WW)      // 3136
#define GPIX (NB*NPIX)    // 100352
#define KDIM (IC*9)       // 1152

#define BNP 448           // pixels per block (8 full rows)
#define PLSTR 9280        // plane stride bytes: 580 px x 16B
#define WINB 37120        // one window buffer bytes (4 planes)

typedef short  bf16x8 __attribute__((ext_vector_type(8)));
typedef float  f32x16 __attribute__((ext_vector_type(16)));
typedef unsigned int u32;

__device__ __forceinline__ unsigned short f2bf(float f) {
  union { float f; unsigned int u; } c; c.f = f;
  unsigned int u = c.u;
  u += 0x7FFFu + ((u >> 16) & 1u);
  return (unsigned short)(u >> 16);
}

__device__ __forceinline__ void gload16(const unsigned short* g, unsigned short* l) {
  __builtin_amdgcn_global_load_lds(
      (const __attribute__((address_space(1))) u32*)g,
      (__attribute__((address_space(3))) u32*)l, 16, 0, 0);
}

// ---- prepass 1a: zero padded border of Xt
__global__ __launch_bounds__(256) void zero_border(unsigned short* __restrict__ Xt, int total) {
  int idx = blockIdx.x * 256 + threadIdx.x;
  if (idx >= total) return;
  int e  = idx & 127;
  int b  = idx >> 7;
  int n  = b / 228;
  int bp = b - n * 228;
  int y, x;
  if (bp < 58)       { y = 0;  x = bp; }
  else if (bp < 116) { y = 57; x = bp - 58; }
  else {
    int b2 = bp - 116;
    y = 1 + (b2 >> 1);
    x = (b2 & 1) * 57;
  }
  Xt[((long)(n * PH + y) * PW + x) * IC + e] = 0;
}

// ---- prepass 1b: NCHW f32 -> NHWC-padded bf16 (LDS-tiled transpose)
__global__ __launch_bounds__(256) void pad_x_nhwc(const float* __restrict__ X,
                                                  unsigned short* __restrict__ Xt) {
  __shared__ float tile[128][65];
  const int t   = threadIdx.x;
  const int p0  = blockIdx.x * 64;
  const int n   = p0 / NPIX;
  const int rem = p0 - n * NPIX;

  const int pixl = t & 63;
  const int q    = t >> 6;
  const float* src = X + ((long)n * IC + q) * NPIX + rem + pixl;
  #pragma unroll
  for (int i = 0; i < 32; ++i)
    tile[q + i * 4][pixl] = src[(long)i * 4 * NPIX];
  __syncthreads();

  const int pix = t >> 2;
  const int icq = (t & 3) * 32;
  int p = rem + pix;
  int y = p / WW, x = p - y * WW;
  unsigned short* dst = Xt + ((long)(n * PH + y + 1) * PW + (x + 1)) * IC + icq;
  #pragma unroll
  for (int g = 0; g < 4; ++g) {
    bf16x8 v;
    #pragma unroll
    for (int j = 0; j < 8; ++j)
      ((unsigned short*)&v)[j] = f2bf(tile[icq + g * 8 + j][pix]);
    *reinterpret_cast<bf16x8*>(dst + g * 8) = v;
  }
}

// ---- prepass 2: W (OIHW f32) -> Wb bf16 [tap][icb][kh][khalf][256 oc][8 ic]
// idx = ((((tap*4+icb)*2+kh)*2+khalf)*256 + oc)*8 + e ; ic = icb*32+kh*16+khalf*8+e
__global__ __launch_bounds__(256) void pack_w(const float* __restrict__ W,
                                              unsigned short* __restrict__ Wb, int total) {
  int idx = blockIdx.x * 256 + threadIdx.x;
  if (idx >= total) return;
  int e     = idx & 7;
  int oc    = (idx >> 3) & 255;
  int khalf = (idx >> 11) & 1;
  int kh    = (idx >> 12) & 1;
  int icb   = (idx >> 13) & 3;
  int tap   = idx >> 15;
  int ic = icb * 32 + kh * 16 + khalf * 8 + e;
  Wb[idx] = f2bf(W[(oc * IC + ic) * 9 + tap]);
}

// ---- main: halo-window implicit GEMM, 32x32x16 MFMA, k-step pipeline
__global__ __launch_bounds__(448, 2) void conv_win(
    const unsigned short* __restrict__ Xt,
    const unsigned short* __restrict__ Wb,
    float* __restrict__ out) {
  __shared__ __align__(16) unsigned short lds[37120];   // 74240 B: 2 window buffers
  char* const ldsb = (char*)lds;

  const int tid  = threadIdx.x;
  const int lane = tid & 63;
  const int wn   = tid >> 6;             // 7 N-waves; wave tile 128oc x 64px
  const int l31  = lane & 31;
  const int lhk  = lane >> 5;            // khalf

  // XCD-aware bijective remap: 448 = 8 x 56
  const int bid = blockIdx.x;
  const int wg  = (bid & 7) * 56 + (bid >> 3);
  const int pt  = wg >> 1;               // 0..223
  const int ocb = (wg & 1) * 128;
  const int n   = pt / 7;
  const int rg  = pt - n * 7;
  const int p0  = rg * BNP;              // pixel base (8-row aligned)
  const int y0  = rg * 8;                // padded top row of window

  // ---- A source: lane reads 16B at [*][khalf=lhk][ocb + m*32 + l31][8e]
  const unsigned short* aBase = Wb + (size_t)lhk * 2048 + (ocb + l31) * 8;

  // ---- window staging sources (6 calls; slots r*448+tid for r<5, 1872+tid for r=5;
  //      overlap 1872..2239 re-written with identical data - benign)
  const unsigned short* srcW[6];
  #pragma unroll
  for (int r = 0; r < 6; ++r) {
    int slot = (r < 5) ? (r * 448 + tid) : (1872 + tid);   // <= 2319
    int plane = slot / 580;
    int pix   = slot - plane * 580;
    int row = pix / 58, col = pix - row * 58;
    srcW[r] = Xt + ((long)((n * PH + y0 + row) * PW + col)) * IC + plane * 8;
  }

  // ---- B fragment base offsets (within window buffer)
  int pixLin[2];
  #pragma unroll
  for (int t = 0; t < 2; ++t) {
    int local = wn * 64 + t * 32 + l31;    // 0..447
    int wy = local / 56, wx = local - wy * 56;
    pixLin[t] = (wy * 58 + wx) * 16;
  }
  const int qoff = lhk * PLSTR;

  f32x16 acc[4][2];
  #pragma unroll
  for (int m = 0; m < 4; ++m)
    #pragma unroll
    for (int t = 0; t < 2; ++t)
      acc[m][t] = (f32x16)(0.f);

  auto stageWin = [&](int icb) {          // slice icb -> buf (icb&1); wave-uniform dest
    char* base = ldsb + (icb & 1) * WINB + (tid & ~63) * 16;
    #pragma unroll
    for (int r = 0; r < 6; ++r)
      gload16(srcW[r] + icb * 32,
              (unsigned short*)(base + ((r < 5) ? r * 448 * 16 : 1872 * 16)));
  };

  // ---- prologue
  stageWin(0);
  bf16x8 aReg[2][4];
  #pragma unroll
  for (int m = 0; m < 4; ++m)
    aReg[0][m] = *(const bf16x8*)(aBase + m * 256);       // (tap0, icb0, kh0)
  asm volatile("s_waitcnt vmcnt(0)" ::: "memory");
  __builtin_amdgcn_s_barrier();
  __builtin_amdgcn_sched_barrier(0);

  bf16x8 bfv[2][2];

  for (int icb = 0; icb < 4; ++icb) {
    const int winSel = (icb & 1) * WINB;

    // slice prologue: B-frags for ks=0 (tap0 kh0; slot 0)
    #pragma unroll
    for (int t = 0; t < 2; ++t)
      bfv[0][t] = *(const bf16x8*)(ldsb + winSel + qoff + pixLin[t]);

    #pragma unroll
    for (int ks = 0; ks < 18; ++ks) {
      const int tap = ks >> 1, kh = ks & 1;           // read slot = kh
      const int psl = kh ^ 1;                         // prefetch slot

      // A prefetch for ks+1
      if (ks < 17) {
        const int nt = (ks + 1) >> 1, nkh = (ks + 1) & 1;
        #pragma unroll
        for (int m = 0; m < 4; ++m)
          aReg[psl][m] = *(const bf16x8*)(aBase
              + (size_t)(((nt * 4 + icb) * 2 + nkh)) * 4096 + m * 256);
      } else if (icb < 3) {
        #pragma unroll
        for (int m = 0; m < 4; ++m)
          aReg[psl][m] = *(const bf16x8*)(aBase + (size_t)((icb + 1) * 2) * 4096 + m * 256);
      }

      // B prefetch for ks+1 (same window; last ks of slice has none)
      if (ks < 17) {
        const int nt = (ks + 1) >> 1, nkh = (ks + 1) & 1;
        const int ndy = nt / 3, ndx = nt - ndy * 3;
        const int noff = nkh * (2 * PLSTR) + (ndy * 58 + ndx) * 16;
        #pragma unroll
        for (int t = 0; t < 2; ++t)
          bfv[psl][t] = *(const bf16x8*)(ldsb + winSel + qoff + pixLin[t] + noff);
      }

      // MFMA burst on current slot
      __builtin_amdgcn_s_setprio(1);
      #pragma unroll
      for (int m = 0; m < 4; ++m)
        #pragma unroll
        for (int t = 0; t < 2; ++t)
          acc[m][t] = __builtin_amdgcn_mfma_f32_32x32x16_bf16(aReg[kh][m], bfv[kh][t],
                                                              acc[m][t], 0, 0, 0);
      __builtin_amdgcn_s_setprio(0);

      // staging mid-slice: A-prefetches issued before it are unaffected; the first
      // A-wait that force-retires staging is 2 k-steps later (~550cy, >= L2 latency)
      if (ks == 9 && icb < 3) stageWin(icb + 1);
    }

    // window(icb+1) fully staged (all waves) before reading; WAR certified for icb+2
    asm volatile("s_waitcnt vmcnt(0)" ::: "memory");
    __builtin_amdgcn_s_barrier();
    __builtin_amdgcn_sched_barrier(0);
  }

  // ---- epilogue: 32x32 C/D: col=lane&31 (pixel), row=(r&3)+8*(r>>2)+4*(lane>>5) (oc)
  #pragma unroll
  for (int t = 0; t < 2; ++t) {
    int pix = p0 + wn * 64 + t * 32 + l31;
    #pragma unroll
    for (int m = 0; m < 4; ++m) {
      #pragma unroll
      for (int r = 0; r < 16; ++r) {
        int oc = ocb + m * 32 + (r & 3) + 8 * (r >> 2) + 4 * lhk;
        out[((long)(n * OC + oc)) * NPIX + pix] = acc[m][t][r];
      }
    }
  }
}

// ---- fallback: naive direct conv fp32
__global__ __launch_bounds__(256) void conv_naive(const float* __restrict__ X,
                                                  const float* __restrict__ W,
                                                  float* __restrict__ out, int total) {
  int idx = blockIdx.x * 256 + threadIdx.x;
  if (idx >= total) return;
  int prow = idx % NPIX;
  int t    = idx / NPIX;
  int oc   = t % OC;
  int n    = t / OC;
  int oh = prow / WW, ow = prow % WW;
  float s = 0.f;
  for (int ic = 0; ic < IC; ++ic) {
    const float* xp = X + ((long)(n * IC + ic)) * NPIX;
    const float* wp = W + ((long)(oc * IC + ic)) * 9;
    #pragma unroll
    for (int kh = 0; kh < 3; ++kh) {
      int ih = oh + kh - 1;
      if (ih < 0 || ih >= HH) continue;
      #pragma unroll
      for (int kw = 0; kw < 3; ++kw) {
        int iw = ow + kw - 1;
        if (iw < 0 || iw >= WW) continue;
        s += xp[ih * WW + iw] * wp[kh * 3 + kw];
      }
    }
  }
  out[idx] = s;
}

extern "C" void kernel_launch(void* const* d_in, const int* in_sizes, int n_in,
                              void* d_out, int out_size, void* d_ws, size_t ws_size,
                              hipStream_t stream) {
  const float* X = (const float*)d_in[0];
  const float* W = (const float*)d_in[1];
  float* out = (float*)d_out;

  const size_t xt_elems = (size_t)NB * PS * IC;
  const size_t wb_elems = (size_t)9 * 4 * 2 * 2 * 256 * 8;   // 294,912
  const size_t need = (xt_elems + wb_elems) * sizeof(unsigned short);

  if (ws_size >= need) {
    unsigned short* Xt = (unsigned short*)d_ws;
    unsigned short* Wb = Xt + xt_elems;

    int totB = NB * 228 * IC;
    zero_border<<<(totB + 255) / 256, 256, 0, stream>>>(Xt, totB);
    pad_x_nhwc<<<GPIX / 64, 256, 0, stream>>>(X, Xt);
    int totW = (int)wb_elems;
    pack_w<<<(totW + 255) / 256, 256, 0, stream>>>(W, Wb, totW);
    conv_win<<<(GPIX / BNP) * 2, 448, 0, stream>>>(Xt, Wb, out);
  } else {
    int tot = NB * OC * NPIX;
    conv_naive<<<(tot + 255) / 256, 256, 0, stream>>>(X, W, out, tot);
  }
}

// Round 14
// 90.220 us; speedup vs baseline: 1.2370x; 1.1412x over previous
//
#include <hip/hip_runtime.h>
#include <hip/hip_bf16.h>

// Conv2d 3x3 s1 p1, NCHW: X(32,128,56,56) f32 * W(256,128,3,3) f32 -> out(32,256,56,56) f32
// R14 = R10 (68.2us best, passing) with ONE change: plane-split window layout
// (R13's proven conflict-killer: 5.2M -> 0.77M conflict cycles).
// Window buffer = 4 ic-octet planes [580px][16B], plane stride 9280B (=2320 dwords
// == 16 mod 32 banks => lh-groups alias max 2-way = free). swz() deleted: staging
// dest linear, reads linear (both-sides-or-neither satisfied trivially).
// Everything else IDENTICAL to R10: 16x16x32 MFMA, 8 waves 2Mx4N, 128oc x 448px,
// aReg[2][4] global-tap-parity dbuf, staging at end of tap 4, ONE vmcnt(0)+
// s_barrier+sched_barrier per ic-slice, XCD-swizzled grid 448.

#define IC 128
#define OC 256
#define HH 56
#define WW 56
#define NB 32
#define PH 58
#define PW 58
#define PS (PH*PW)
#define NPIX (HH*WW)      // 3136
#define GPIX (NB*NPIX)    // 100352
#define KDIM (IC*9)       // 1152

#define BMH 128           // oc per block
#define BNP 448           // pixels per block (8 rows x 56)

#define PLSTR 9280        // plane stride bytes: 580 px x 16B
#define WCONT 2320        // content slots (4 planes x 580)
#define WINB 37888        // buffer bytes: 2368 slots (48 slack for wave-granular staging)

typedef short  bf16x8 __attribute__((ext_vector_type(8)));
typedef float  f32x4  __attribute__((ext_vector_type(4)));
typedef unsigned int u32;

__device__ __forceinline__ unsigned short f2bf(float f) {
  union { float f; unsigned int u; } c; c.f = f;
  unsigned int u = c.u;
  u += 0x7FFFu + ((u >> 16) & 1u);
  return (unsigned short)(u >> 16);
}

__device__ __forceinline__ void gload16(const unsigned short* g, unsigned short* l) {
  __builtin_amdgcn_global_load_lds(
      (const __attribute__((address_space(1))) u32*)g,
      (__attribute__((address_space(3))) u32*)l, 16, 0, 0);
}

// ---- prepass 1a: zero padded border of Xt
__global__ __launch_bounds__(256) void zero_border(unsigned short* __restrict__ Xt, int total) {
  int idx = blockIdx.x * 256 + threadIdx.x;
  if (idx >= total) return;
  int e  = idx & 127;
  int b  = idx >> 7;
  int n  = b / 228;
  int bp = b - n * 228;
  int y, x;
  if (bp < 58)       { y = 0;  x = bp; }
  else if (bp < 116) { y = 57; x = bp - 58; }
  else {
    int b2 = bp - 116;
    y = 1 + (b2 >> 1);
    x = (b2 & 1) * 57;
  }
  Xt[((long)(n * PH + y) * PW + x) * IC + e] = 0;
}

// ---- prepass 1b: NCHW f32 -> NHWC-padded bf16 (LDS-tiled transpose)
__global__ __launch_bounds__(256) void pad_x_nhwc(const float* __restrict__ X,
                                                  unsigned short* __restrict__ Xt) {
  __shared__ float tile[128][65];
  const int t   = threadIdx.x;
  const int p0  = blockIdx.x * 64;
  const int n   = p0 / NPIX;
  const int rem = p0 - n * NPIX;

  const int pixl = t & 63;
  const int q    = t >> 6;
  const float* src = X + ((long)n * IC + q) * NPIX + rem + pixl;
  #pragma unroll
  for (int i = 0; i < 32; ++i)
    tile[q + i * 4][pixl] = src[(long)i * 4 * NPIX];
  __syncthreads();

  const int pix = t >> 2;
  const int icq = (t & 3) * 32;
  int p = rem + pix;
  int y = p / WW, x = p - y * WW;
  unsigned short* dst = Xt + ((long)(n * PH + y + 1) * PW + (x + 1)) * IC + icq;
  #pragma unroll
  for (int g = 0; g < 4; ++g) {
    bf16x8 v;
    #pragma unroll
    for (int j = 0; j < 8; ++j)
      ((unsigned short*)&v)[j] = f2bf(tile[icq + g * 8 + j][pix]);
    *reinterpret_cast<bf16x8*>(dst + g * 8) = v;
  }
}

// ---- prepass 2: W (OIHW f32) -> Wb bf16 [tap][ic_octet s][oc][8 ic]
__global__ __launch_bounds__(256) void pack_w(const float* __restrict__ W,
                                              unsigned short* __restrict__ Wb, int total) {
  int idx = blockIdx.x * 256 + threadIdx.x;
  if (idx >= total) return;
  int e  = idx & 7;
  int oc = (idx >> 3) & 255;
  int s  = (idx >> 11) & 15;
  int t  = idx >> 15;
  Wb[idx] = f2bf(W[(oc * IC + s * 8 + e) * 9 + t]);
}

// ---- main: halo-window implicit GEMM, plane-split window
__global__ __launch_bounds__(512) void conv_win(
    const unsigned short* __restrict__ Xt,
    const unsigned short* __restrict__ Wb,
    float* __restrict__ out) {
  __shared__ __align__(16) unsigned short lds[37888];   // 75776 B: 2 window buffers
  char* const ldsb = (char*)lds;

  const int tid  = threadIdx.x;
  const int lane = tid & 63;
  const int w    = tid >> 6;
  const int wm = w >> 2, wn = w & 3;     // 2M x 4N wave grid; wave tile 64oc x 112px
  const int l15 = lane & 15, lh = lane >> 4;

  // XCD-aware bijective remap: 448 = 8 x 56
  const int bid   = blockIdx.x;
  const int wg    = (bid & 7) * 56 + (bid >> 3);
  const int ntile = wg >> 1;             // 0..223
  const int mhalf = wg & 1;
  const int n   = ntile / 7;
  const int rg  = ntile - n * 7;
  const int y0  = rg * 8;                // padded top row of window
  const int ocb = mhalf * BMH;

  // ---- A source: per-lane VGPR loads, coalesced (16 lanes x 16B contiguous)
  const unsigned short* aBase = Wb + (size_t)lh * 2048 + (ocb + wm * 64 + l15) * 8;

  // ---- window staging sources (5 slots/thread; content = 4 planes x [10][58][16B])
  const unsigned short* srcW[5];
  #pragma unroll
  for (int r = 0; r < 5; ++r) {
    int s = tid + r * 512;
    if (s >= WCONT) s = WCONT - 1;               // slack slots: dup (never read)
    int plane = s / 580;
    int pix   = s - plane * 580;
    int row = pix / 58, col = pix - row * 58;
    srcW[r] = Xt + ((long)((n * PH + y0 + row) * PW + col)) * IC + plane * 8;
  }

  // ---- fragment offsets (plane-split: lh = ic-octet plane)
  int pixLin[7];
  #pragma unroll
  for (int j = 0; j < 7; ++j) {
    int local = wn * 112 + j * 16 + l15;     // 0..447 within block
    int wy = local / 56, wx = local - wy * 56;
    pixLin[j] = lh * PLSTR + (wy * 58 + wx) * 16;
  }

  f32x4 acc[4][7];
  #pragma unroll
  for (int m = 0; m < 4; ++m)
    #pragma unroll
    for (int j = 0; j < 7; ++j)
      acc[m][j] = (f32x4){0.f, 0.f, 0.f, 0.f};

  auto stageWin = [&](int icb) {          // slice icb -> buf (icb&1); wave-uniform dest
    char* base = ldsb + (icb & 1) * WINB + (tid & ~63) * 16;
    #pragma unroll
    for (int r = 0; r < 5; ++r)
      if (r < 4 || w <= 4)                // call 4: waves 5-7 skip (beyond 2368 slots)
        gload16(srcW[r] + icb * 32, (unsigned short*)(base + r * 8192));
  };

  // ---- prologue
  stageWin(0);
  bf16x8 aReg[2][4];
  #pragma unroll
  for (int m = 0; m < 4; ++m)
    aReg[0][m] = *(const bf16x8*)(aBase + m * 128);        // A(q=0): tap0, icb0
  asm volatile("s_waitcnt vmcnt(0)" ::: "memory");
  __builtin_amdgcn_s_barrier();
  __builtin_amdgcn_sched_barrier(0);

  for (int icb = 0; icb < 4; ++icb) {
    const int winSel = (icb & 1) * WINB;

    #pragma unroll
    for (int tap = 0; tap < 9; ++tap) {
      // global tap parity: q = icb*9+tap ; 9 odd => q&1 == (icb+tap)&1
      const int rs = (icb + tap) & 1;          // read slot
      const int ps = rs ^ 1;                   // prefetch slot (q+1)

      // prefetch A for q+1 (never collides: ps != rs)
      if (tap < 8) {
        #pragma unroll
        for (int m = 0; m < 4; ++m)
          aReg[ps][m] = *(const bf16x8*)(aBase + (size_t)(tap + 1) * 32768
                                               + (size_t)icb * 8192 + m * 128);
      } else if (icb < 3) {
        #pragma unroll
        for (int m = 0; m < 4; ++m)
          aReg[ps][m] = *(const bf16x8*)(aBase + (size_t)(icb + 1) * 8192 + m * 128);
      }

      const int dy = tap / 3, dx = tap - dy * 3;   // compile-time (tap unrolled)
      const int toff = (dy * 58 + dx) * 16;

      bf16x8 bfv[7];
      #pragma unroll
      for (int j = 0; j < 7; ++j)
        bfv[j] = *(const bf16x8*)(ldsb + winSel + pixLin[j] + toff);

      __builtin_amdgcn_s_setprio(1);
      #pragma unroll
      for (int j = 0; j < 7; ++j)
        #pragma unroll
        for (int m = 0; m < 4; ++m)
          acc[m][j] = __builtin_amdgcn_mfma_f32_16x16x32_bf16(aReg[rs][m], bfv[j],
                                                              acc[m][j], 0, 0, 0);
      __builtin_amdgcn_s_setprio(0);

      // FIFO-aware staging: issue after tap 4 so A-prefetch waits at taps<=5 do not
      // force-retire the staging burst (vmcnt retires oldest-first).
      if (tap == 4 && icb < 3) stageWin(icb + 1);
    }

    // window(icb+1) fully staged (all waves) before reading it; WAR on buf icb&1
    // certified for the stage at icb+2 by this same barrier.
    asm volatile("s_waitcnt vmcnt(0)" ::: "memory");
    __builtin_amdgcn_s_barrier();
    __builtin_amdgcn_sched_barrier(0);
  }

  // ---- epilogue: D row=(lane>>4)*4+reg (oc), col=lane&15 (pixel)
  #pragma unroll
  for (int j = 0; j < 7; ++j) {
    int local = wn * 112 + j * 16 + l15;
    int pidx  = rg * BNP + local;                 // pixel within image
    #pragma unroll
    for (int m = 0; m < 4; ++m) {
      int oc = ocb + wm * 64 + m * 16 + lh * 4;
      float* op = out + ((long)(n * OC + oc)) * NPIX + pidx;
      #pragma unroll
      for (int r = 0; r < 4; ++r)
        op[(long)r * NPIX] = acc[m][j][r];
    }
  }
}

// ---- fallback: naive direct conv fp32
__global__ __launch_bounds__(256) void conv_naive(const float* __restrict__ X,
                                                  const float* __restrict__ W,
                                                  float* __restrict__ out, int total) {
  int idx = blockIdx.x * 256 + threadIdx.x;
  if (idx >= total) return;
  int prow = idx % NPIX;
  int t    = idx / NPIX;
  int oc   = t % OC;
  int n    = t / OC;
  int oh = prow / WW, ow = prow % WW;
  float s = 0.f;
  for (int ic = 0; ic < IC; ++ic) {
    const float* xp = X + ((long)(n * IC + ic)) * NPIX;
    const float* wp = W + ((long)(oc * IC + ic)) * 9;
    #pragma unroll
    for (int kh = 0; kh < 3; ++kh) {
      int ih = oh + kh - 1;
      if (ih < 0 || ih >= HH) continue;
      #pragma unroll
      for (int kw = 0; kw < 3; ++kw) {
        int iw = ow + kw - 1;
        if (iw < 0 || iw >= WW) continue;
        s += xp[ih * WW + iw] * wp[kh * 3 + kw];
      }
    }
  }
  out[idx] = s;
}

extern "C" void kernel_launch(void* const* d_in, const int* in_sizes, int n_in,
                              void* d_out, int out_size, void* d_ws, size_t ws_size,
                              hipStream_t stream) {
  const float* X = (const float*)d_in[0];
  const float* W = (const float*)d_in[1];
  float* out = (float*)d_out;

  const size_t xt_elems = (size_t)NB * PS * IC;
  const size_t wb_elems = (size_t)9 * 16 * 256 * 8;   // 294,912
  const size_t need = (xt_elems + wb_elems) * sizeof(unsigned short);

  if (ws_size >= need) {
    unsigned short* Xt = (unsigned short*)d_ws;
    unsigned short* Wb = Xt + xt_elems;

    int totB = NB * 228 * IC;
    zero_border<<<(totB + 255) / 256, 256, 0, stream>>>(Xt, totB);
    pad_x_nhwc<<<GPIX / 64, 256, 0, stream>>>(X, Xt);
    int totW = (int)wb_elems;
    pack_w<<<(totW + 255) / 256, 256, 0, stream>>>(W, Wb, totW);
    conv_win<<<(GPIX / BNP) * (OC / BMH), 512, 0, stream>>>(Xt, Wb, out);
  } else {
    int tot = NB * OC * NPIX;
    conv_naive<<<(tot + 255) / 256, 256, 0, stream>>>(X, W, out, tot);
  }
}

// Round 15
// 86.389 us; speedup vs baseline: 1.2918x; 1.0444x over previous
//
#include <hip/hip_runtime.h>
#include <hip/hip_bf16.h>

// Conv2d 3x3 s1 p1, NCHW: X(32,128,56,56) f32 * W(256,128,3,3) f32 -> out(32,256,56,56) f32
// R15 = R10 (68.2us, best) + ONE timing probe: anti-phase wave stagger.
// Hypothesis: slice barriers re-sync the 2 waves/SIMD; identical code => identical
// phase => both waves read/wait simultaneously (MFMA pipe idle), then serialize
// MFMA bursts. Wall ~ R+2M (2600cy/tap) instead of max(R,2M) (~1560cy).
// Probe: wm=1 waves (SIMD-paired with wm=0 under round-robin dispatch) s_sleep ~768cy
// after each barrier => persistent half-tap offset => cross-wave MFMA/read overlap
// (m114). Cost if false: ~3us. Everything else byte-identical to R10.

#define IC 128
#define OC 256
#define HH 56
#define WW 56
#define NB 32
#define PH 58
#define PW 58
#define PS (PH*PW)
#define NPIX (HH*WW)      // 3136
#define GPIX (NB*NPIX)    // 100352
#define KDIM (IC*9)       // 1152

#define BMH 128           // oc per block
#define BNP 448           // pixels per block (8 rows x 56)

#define WROWB 3712        // window row stride bytes: 58 cols x 64B
#define WINREAL 37120     // 10 rows x 3712
#define WINB 37888        // buffer size incl. staging slack

typedef short  bf16x8 __attribute__((ext_vector_type(8)));
typedef float  f32x4  __attribute__((ext_vector_type(4)));
typedef unsigned int u32;

__device__ __forceinline__ unsigned short f2bf(float f) {
  union { float f; unsigned int u; } c; c.f = f;
  unsigned int u = c.u;
  u += 0x7FFFu + ((u >> 16) & 1u);
  return (unsigned short)(u >> 16);
}

__device__ __forceinline__ void gload16(const unsigned short* g, unsigned short* l) {
  __builtin_amdgcn_global_load_lds(
      (const __attribute__((address_space(1))) u32*)g,
      (__attribute__((address_space(3))) u32*)l, 16, 0, 0);
}

// involution on bytes: bits 4-7 ^= bits 8-11
__device__ __forceinline__ int swz(int a) { return a ^ (((a >> 8) & 15) << 4); }

// ---- prepass 1a: zero padded border of Xt
__global__ __launch_bounds__(256) void zero_border(unsigned short* __restrict__ Xt, int total) {
  int idx = blockIdx.x * 256 + threadIdx.x;
  if (idx >= total) return;
  int e  = idx & 127;
  int b  = idx >> 7;
  int n  = b / 228;
  int bp = b - n * 228;
  int y, x;
  if (bp < 58)       { y = 0;  x = bp; }
  else if (bp < 116) { y = 57; x = bp - 58; }
  else {
    int b2 = bp - 116;
    y = 1 + (b2 >> 1);
    x = (b2 & 1) * 57;
  }
  Xt[((long)(n * PH + y) * PW + x) * IC + e] = 0;
}

// ---- prepass 1b: NCHW f32 -> NHWC-padded bf16 (LDS-tiled transpose)
__global__ __launch_bounds__(256) void pad_x_nhwc(const float* __restrict__ X,
                                                  unsigned short* __restrict__ Xt) {
  __shared__ float tile[128][65];
  const int t   = threadIdx.x;
  const int p0  = blockIdx.x * 64;
  const int n   = p0 / NPIX;
  const int rem = p0 - n * NPIX;

  const int pixl = t & 63;
  const int q    = t >> 6;
  const float* src = X + ((long)n * IC + q) * NPIX + rem + pixl;
  #pragma unroll
  for (int i = 0; i < 32; ++i)
    tile[q + i * 4][pixl] = src[(long)i * 4 * NPIX];
  __syncthreads();

  const int pix = t >> 2;
  const int icq = (t & 3) * 32;
  int p = rem + pix;
  int y = p / WW, x = p - y * WW;
  unsigned short* dst = Xt + ((long)(n * PH + y + 1) * PW + (x + 1)) * IC + icq;
  #pragma unroll
  for (int g = 0; g < 4; ++g) {
    bf16x8 v;
    #pragma unroll
    for (int j = 0; j < 8; ++j)
      ((unsigned short*)&v)[j] = f2bf(tile[icq + g * 8 + j][pix]);
    *reinterpret_cast<bf16x8*>(dst + g * 8) = v;
  }
}

// ---- prepass 2: W (OIHW f32) -> Wb bf16 [tap][ic_octet s][oc][8 ic]
__global__ __launch_bounds__(256) void pack_w(const float* __restrict__ W,
                                              unsigned short* __restrict__ Wb, int total) {
  int idx = blockIdx.x * 256 + threadIdx.x;
  if (idx >= total) return;
  int e  = idx & 7;
  int oc = (idx >> 3) & 255;
  int s  = (idx >> 11) & 15;
  int t  = idx >> 15;
  Wb[idx] = f2bf(W[(oc * IC + s * 8 + e) * 9 + t]);
}

// ---- main: halo-window implicit GEMM
__global__ __launch_bounds__(512) void conv_win(
    const unsigned short* __restrict__ Xt,
    const unsigned short* __restrict__ Wb,
    float* __restrict__ out) {
  __shared__ __align__(16) unsigned short lds[37888];   // 75776 B: 2 window buffers
  char* const ldsb = (char*)lds;

  const int tid  = threadIdx.x;
  const int lane = tid & 63;
  const int w    = tid >> 6;
  const int wm = w >> 2, wn = w & 3;     // 2M x 4N wave grid; wave tile 64oc x 112px
  const int l15 = lane & 15, lh = lane >> 4;

  // XCD-aware bijective remap: 448 = 8 x 56
  const int bid   = blockIdx.x;
  const int wg    = (bid & 7) * 56 + (bid >> 3);
  const int ntile = wg >> 1;             // 0..223
  const int mhalf = wg & 1;
  const int n   = ntile / 7;
  const int rg  = ntile - n * 7;
  const int y0  = rg * 8;                // padded top row of window
  const int ocb = mhalf * BMH;

  // ---- A source: per-lane VGPR loads, coalesced (16 lanes x 16B contiguous)
  const unsigned short* aBase = Wb + (size_t)lh * 2048 + (ocb + wm * 64 + l15) * 8;

  // ---- window staging sources (5 slots/thread; content layout [10][58 cols][64B])
  const unsigned short* srcW[5];
  #pragma unroll
  for (int r = 0; r < 5; ++r) {
    int xw = swz((tid + r * 512) * 16);
    if (xw >= WINREAL) xw = WINREAL - 16;          // slack slots: dup last (never read)
    int row = xw / WROWB;
    int rem = xw - row * WROWB;
    int col = rem >> 6;
    srcW[r] = Xt + ((long)((n * PH + y0 + row) * PW + col)) * IC + ((rem & 63) >> 1);
  }

  // ---- fragment linear offsets (window, stride-58 rows)
  int pixLin[7];
  #pragma unroll
  for (int j = 0; j < 7; ++j) {
    int local = wn * 112 + j * 16 + l15;     // 0..447 within block
    int wy = local / 56, wx = local - wy * 56;
    pixLin[j] = (wy * 58 + wx) * 64 + lh * 16;
  }

  f32x4 acc[4][7];
  #pragma unroll
  for (int m = 0; m < 4; ++m)
    #pragma unroll
    for (int j = 0; j < 7; ++j)
      acc[m][j] = (f32x4){0.f, 0.f, 0.f, 0.f};

  auto stageWin = [&](int icb) {          // slice icb -> buf (icb&1); wave-uniform dest
    char* base = ldsb + (icb & 1) * WINB + (tid & ~63) * 16;
    #pragma unroll
    for (int r = 0; r < 5; ++r)
      if (r < 4 || w <= 4)                // call 4: waves 5-7 skip (slots beyond slack)
        gload16(srcW[r] + icb * 32, (unsigned short*)(base + r * 8192));
  };

  // ---- prologue
  stageWin(0);
  bf16x8 aReg[2][4];
  #pragma unroll
  for (int m = 0; m < 4; ++m)
    aReg[0][m] = *(const bf16x8*)(aBase + m * 128);        // A(q=0): tap0, icb0
  asm volatile("s_waitcnt vmcnt(0)" ::: "memory");
  __builtin_amdgcn_s_barrier();
  __builtin_amdgcn_sched_barrier(0);
  if (wm) asm volatile("s_sleep 12");     // anti-phase stagger (~768 cy)

  for (int icb = 0; icb < 4; ++icb) {
    const int winSel = (icb & 1) * WINB;

    #pragma unroll
    for (int tap = 0; tap < 9; ++tap) {
      // global tap parity: q = icb*9+tap ; 9 odd => q&1 == (icb+tap)&1
      const int rs = (icb + tap) & 1;          // read slot
      const int ps = rs ^ 1;                   // prefetch slot (q+1)

      // prefetch A for q+1 (never collides: ps != rs)
      if (tap < 8) {
        #pragma unroll
        for (int m = 0; m < 4; ++m)
          aReg[ps][m] = *(const bf16x8*)(aBase + (size_t)(tap + 1) * 32768
                                               + (size_t)icb * 8192 + m * 128);
      } else if (icb < 3) {
        #pragma unroll
        for (int m = 0; m < 4; ++m)
          aReg[ps][m] = *(const bf16x8*)(aBase + (size_t)(icb + 1) * 8192 + m * 128);
      }

      const int dy = tap / 3, dx = tap - dy * 3;   // compile-time (tap unrolled)
      const int toff = (dy * 58 + dx) * 64;

      bf16x8 bfv[7];
      #pragma unroll
      for (int j = 0; j < 7; ++j)
        bfv[j] = *(const bf16x8*)(ldsb + winSel + swz(pixLin[j] + toff));

      __builtin_amdgcn_s_setprio(1);
      #pragma unroll
      for (int j = 0; j < 7; ++j)
        #pragma unroll
        for (int m = 0; m < 4; ++m)
          acc[m][j] = __builtin_amdgcn_mfma_f32_16x16x32_bf16(aReg[rs][m], bfv[j],
                                                              acc[m][j], 0, 0, 0);
      __builtin_amdgcn_s_setprio(0);

      // FIFO-aware staging: issue after tap 4 so A-prefetch waits at taps<=5 do not
      // force-retire the staging burst (vmcnt retires oldest-first).
      if (tap == 4 && icb < 3) stageWin(icb + 1);
    }

    // window(icb+1) fully staged (all waves) before reading it; WAR on buf icb&1
    // certified for the stage at icb+2 by this same barrier.
    asm volatile("s_waitcnt vmcnt(0)" ::: "memory");
    __builtin_amdgcn_s_barrier();
    __builtin_amdgcn_sched_barrier(0);
    if (icb < 3 && wm) asm volatile("s_sleep 12");   // re-stagger after re-sync
  }

  // ---- epilogue: D row=(lane>>4)*4+reg (oc), col=lane&15 (pixel)
  #pragma unroll
  for (int j = 0; j < 7; ++j) {
    int local = wn * 112 + j * 16 + l15;
    int pidx  = rg * BNP + local;                 // pixel within image
    #pragma unroll
    for (int m = 0; m < 4; ++m) {
      int oc = ocb + wm * 64 + m * 16 + lh * 4;
      float* op = out + ((long)(n * OC + oc)) * NPIX + pidx;
      #pragma unroll
      for (int r = 0; r < 4; ++r)
        op[(long)r * NPIX] = acc[m][j][r];
    }
  }
}

// ---- fallback: naive direct conv fp32
__global__ __launch_bounds__(256) void conv_naive(const float* __restrict__ X,
                                                  const float* __restrict__ W,
                                                  float* __restrict__ out, int total) {
  int idx = blockIdx.x * 256 + threadIdx.x;
  if (idx >= total) return;
  int prow = idx % NPIX;
  int t    = idx / NPIX;
  int oc   = t % OC;
  int n    = t / OC;
  int oh = prow / WW, ow = prow % WW;
  float s = 0.f;
  for (int ic = 0; ic < IC; ++ic) {
    const float* xp = X + ((long)(n * IC + ic)) * NPIX;
    const float* wp = W + ((long)(oc * IC + ic)) * 9;
    #pragma unroll
    for (int kh = 0; kh < 3; ++kh) {
      int ih = oh + kh - 1;
      if (ih < 0 || ih >= HH) continue;
      #pragma unroll
      for (int kw = 0; kw < 3; ++kw) {
        int iw = ow + kw - 1;
        if (iw < 0 || iw >= WW) continue;
        s += xp[ih * WW + iw] * wp[kh * 3 + kw];
      }
    }
  }
  out[idx] = s;
}

extern "C" void kernel_launch(void* const* d_in, const int* in_sizes, int n_in,
                              void* d_out, int out_size, void* d_ws, size_t ws_size,
                              hipStream_t stream) {
  const float* X = (const float*)d_in[0];
  const float* W = (const float*)d_in[1];
  float* out = (float*)d_out;

  const size_t xt_elems = (size_t)NB * PS * IC;
  const size_t wb_elems = (size_t)9 * 16 * 256 * 8;   // 294,912
  const size_t need = (xt_elems + wb_elems) * sizeof(unsigned short);

  if (ws_size >= need) {
    unsigned short* Xt = (unsigned short*)d_ws;
    unsigned short* Wb = Xt + xt_elems;

    int totB = NB * 228 * IC;
    zero_border<<<(totB + 255) / 256, 256, 0, stream>>>(Xt, totB);
    pad_x_nhwc<<<GPIX / 64, 256, 0, stream>>>(X, Xt);
    int totW = (int)wb_elems;
    pack_w<<<(totW + 255) / 256, 256, 0, stream>>>(W, Wb, totW);
    conv_win<<<(GPIX / BNP) * (OC / BMH), 512, 0, stream>>>(Xt, Wb, out);
  } else {
    int tot = NB * OC * NPIX;
    conv_naive<<<(tot + 255) / 256, 256, 0, stream>>>(X, W, out, tot);
  }
}

// Round 16
// 84.517 us; speedup vs baseline: 1.3204x; 1.0221x over previous
//
#include <hip/hip_runtime.h>
#include <hip/hip_bf16.h>

// Conv2d 3x3 s1 p1, NCHW: X(32,128,56,56) f32 * W(256,128,3,3) f32 -> out(32,256,56,56) f32
// R16: many-small-blocks decomposition. GPIX=2^11*7^2 => grid 1792 = 7*256 packs 100%
// (R10's 448 = 1.75*256 => 87.5% ceiling). Block = 128oc x 112px (2 out rows), 2 waves;
// wave tile 64oc x 112px IDENTICAL to R10 (acc 112 + ~128 arch regs => 2 waves/SIMD).
// 4 independent blocks resident per CU (LDS 32KB each) with independent barriers =>
// natural wave de-phasing (s_sleep probe failed; independence is the robust version).
// Window [4 rows][58 cols][64B] = 14848B, WINB 16384. Body = R10 verbatim: aReg parity
// prefetch from L2, swz'd window reads, staging after tap 4, one vmcnt(0)+barrier/slice.
// Prepass: border-zero FUSED into pad kernel (one launch fewer).

#define IC 128
#define OC 256
#define HH 56
#define WW 56
#define NB 32
#define PH 58
#define PW 58
#define PS (PH*PW)
#define NPIX (HH*WW)      // 3136
#define GPIX (NB*NPIX)    // 100352
#define KDIM (IC*9)       // 1152

#define BNP 112           // pixels per block (2 rows of 56)
#define WROWB 3712        // window row stride bytes: 58 cols x 64B
#define WINREAL 14848     // 4 rows x 3712
#define WINB 16384        // buffer stride (1024 slots of 16B; 96 slack)

#define PADBLK 1568       // interior pad blocks (GPIX/64)
#define BORDBLK 456       // border blocks: 32*228*16 slots / 256

typedef short  bf16x8 __attribute__((ext_vector_type(8)));
typedef float  f32x4  __attribute__((ext_vector_type(4)));
typedef unsigned int u32;

__device__ __forceinline__ unsigned short f2bf(float f) {
  union { float f; unsigned int u; } c; c.f = f;
  unsigned int u = c.u;
  u += 0x7FFFu + ((u >> 16) & 1u);
  return (unsigned short)(u >> 16);
}

__device__ __forceinline__ void gload16(const unsigned short* g, unsigned short* l) {
  __builtin_amdgcn_global_load_lds(
      (const __attribute__((address_space(1))) u32*)g,
      (__attribute__((address_space(3))) u32*)l, 16, 0, 0);
}

// involution on bytes: bits 4-7 ^= bits 8-11 (applied to content offsets only)
__device__ __forceinline__ int swz(int a) { return a ^ (((a >> 8) & 15) << 4); }

// ---- prepass 1 (fused): NCHW f32 -> NHWC-padded bf16 transpose + border zeroing
__global__ __launch_bounds__(256) void pad_x_nhwc(const float* __restrict__ X,
                                                  unsigned short* __restrict__ Xt) {
  if (blockIdx.x >= PADBLK) {
    // border zeroing: slot = 16B chunk of a border pixel's 128-ic row
    int slot = (blockIdx.x - PADBLK) * 256 + threadIdx.x;
    if (slot >= NB * 228 * 16) return;
    int n  = slot / 3648;
    int r  = slot - n * 3648;
    int bp = r >> 4;
    int e8 = r & 15;
    int y, x;
    if (bp < 58)       { y = 0;  x = bp; }
    else if (bp < 116) { y = 57; x = bp - 58; }
    else {
      int b2 = bp - 116;
      y = 1 + (b2 >> 1);
      x = (b2 & 1) * 57;
    }
    bf16x8 z = (bf16x8)(short)0;
    *reinterpret_cast<bf16x8*>(
        Xt + ((long)(n * PH + y) * PW + x) * IC + e8 * 8) = z;
    return;
  }

  __shared__ float tile[128][65];
  const int t   = threadIdx.x;
  const int p0  = blockIdx.x * 64;
  const int n   = p0 / NPIX;
  const int rem = p0 - n * NPIX;

  const int pixl = t & 63;
  const int q    = t >> 6;
  const float* src = X + ((long)n * IC + q) * NPIX + rem + pixl;
  #pragma unroll
  for (int i = 0; i < 32; ++i)
    tile[q + i * 4][pixl] = src[(long)i * 4 * NPIX];
  __syncthreads();

  const int pix = t >> 2;
  const int icq = (t & 3) * 32;
  int p = rem + pix;
  int y = p / WW, x = p - y * WW;
  unsigned short* dst = Xt + ((long)(n * PH + y + 1) * PW + (x + 1)) * IC + icq;
  #pragma unroll
  for (int g = 0; g < 4; ++g) {
    bf16x8 v;
    #pragma unroll
    for (int j = 0; j < 8; ++j)
      ((unsigned short*)&v)[j] = f2bf(tile[icq + g * 8 + j][pix]);
    *reinterpret_cast<bf16x8*>(dst + g * 8) = v;
  }
}

// ---- prepass 2: W (OIHW f32) -> Wb bf16 [tap][ic_octet s][oc][8 ic]
__global__ __launch_bounds__(256) void pack_w(const float* __restrict__ W,
                                              unsigned short* __restrict__ Wb, int total) {
  int idx = blockIdx.x * 256 + threadIdx.x;
  if (idx >= total) return;
  int e  = idx & 7;
  int oc = (idx >> 3) & 255;
  int s  = (idx >> 11) & 15;
  int t  = idx >> 15;
  Wb[idx] = f2bf(W[(oc * IC + s * 8 + e) * 9 + t]);
}

// ---- main: halo-window implicit GEMM, 128oc x 112px blocks, 2 waves
__global__ __launch_bounds__(128) void conv_win(
    const unsigned short* __restrict__ Xt,
    const unsigned short* __restrict__ Wb,
    float* __restrict__ out) {
  __shared__ __align__(16) unsigned short lds[16384];   // 32 KB: 2 window buffers
  char* const ldsb = (char*)lds;

  const int tid  = threadIdx.x;
  const int lane = tid & 63;
  const int wm   = tid >> 6;             // 2 waves: M halves; wave tile 64oc x 112px
  const int l15 = lane & 15, lh = lane >> 4;

  // XCD-aware bijective remap: 1792 = 8 x 224; wg pairs share a pixel tile
  const int bid = blockIdx.x;
  const int wg  = (bid & 7) * 224 + (bid >> 3);
  const int pt  = wg >> 1;               // pixel-tile 0..895
  const int ocb = (wg & 1) * 128;
  const int n   = pt / 28;
  const int rt  = pt - n * 28;           // row-pair within image
  const int y0  = rt * 2;                // padded top row of window (4 rows)

  // ---- A source: per-lane VGPR loads, coalesced (16 lanes x 16B contiguous)
  const unsigned short* aBase = Wb + (size_t)lh * 2048 + (ocb + wm * 64 + l15) * 8;

  // ---- window staging sources (8 slots/thread; content layout [4][58 cols][64B])
  const unsigned short* srcW[8];
  #pragma unroll
  for (int r = 0; r < 8; ++r) {
    int xw = swz((r * 128 + tid) * 16);
    if (xw >= WINREAL) xw = WINREAL - 16;          // slack slots: dup (never read)
    int row = xw / WROWB;
    int rem = xw - row * WROWB;
    int col = rem >> 6;
    srcW[r] = Xt + ((long)((n * PH + y0 + row) * PW + col)) * IC + ((rem & 63) >> 1);
  }

  // ---- fragment linear offsets (window, stride-58 rows)
  int pixLin[7];
  #pragma unroll
  for (int j = 0; j < 7; ++j) {
    int local = j * 16 + l15;                // 0..111 within block
    int wy = local / 56, wx = local - wy * 56;
    pixLin[j] = (wy * 58 + wx) * 64 + lh * 16;
  }

  f32x4 acc[4][7];
  #pragma unroll
  for (int m = 0; m < 4; ++m)
    #pragma unroll
    for (int j = 0; j < 7; ++j)
      acc[m][j] = (f32x4){0.f, 0.f, 0.f, 0.f};

  auto stageWin = [&](int icb) {          // slice icb -> buf (icb&1); wave-uniform dest
    char* base = ldsb + (icb & 1) * WINB + (tid & ~63) * 16;
    #pragma unroll
    for (int r = 0; r < 8; ++r)
      gload16(srcW[r] + icb * 32, (unsigned short*)(base + r * 2048));
  };

  // ---- prologue
  stageWin(0);
  bf16x8 aReg[2][4];
  #pragma unroll
  for (int m = 0; m < 4; ++m)
    aReg[0][m] = *(const bf16x8*)(aBase + m * 128);        // A(q=0): tap0, icb0
  asm volatile("s_waitcnt vmcnt(0)" ::: "memory");
  __builtin_amdgcn_s_barrier();
  __builtin_amdgcn_sched_barrier(0);

  for (int icb = 0; icb < 4; ++icb) {
    const int winSel = (icb & 1) * WINB;

    #pragma unroll
    for (int tap = 0; tap < 9; ++tap) {
      // global tap parity: q = icb*9+tap ; 9 odd => q&1 == (icb+tap)&1
      const int rs = (icb + tap) & 1;          // read slot
      const int ps = rs ^ 1;                   // prefetch slot (q+1)

      // prefetch A for q+1 (never collides: ps != rs)
      if (tap < 8) {
        #pragma unroll
        for (int m = 0; m < 4; ++m)
          aReg[ps][m] = *(const bf16x8*)(aBase + (size_t)(tap + 1) * 32768
                                               + (size_t)icb * 8192 + m * 128);
      } else if (icb < 3) {
        #pragma unroll
        for (int m = 0; m < 4; ++m)
          aReg[ps][m] = *(const bf16x8*)(aBase + (size_t)(icb + 1) * 8192 + m * 128);
      }

      const int dy = tap / 3, dx = tap - dy * 3;   // compile-time (tap unrolled)
      const int toff = (dy * 58 + dx) * 64;

      bf16x8 bfv[7];
      #pragma unroll
      for (int j = 0; j < 7; ++j)
        bfv[j] = *(const bf16x8*)(ldsb + winSel + swz(pixLin[j] + toff));

      __builtin_amdgcn_s_setprio(1);
      #pragma unroll
      for (int j = 0; j < 7; ++j)
        #pragma unroll
        for (int m = 0; m < 4; ++m)
          acc[m][j] = __builtin_amdgcn_mfma_f32_16x16x32_bf16(aReg[rs][m], bfv[j],
                                                              acc[m][j], 0, 0, 0);
      __builtin_amdgcn_s_setprio(0);

      // FIFO-aware staging: issue after tap 4 so A-prefetch waits at taps<=5 do not
      // force-retire the staging burst (vmcnt retires oldest-first).
      if (tap == 4 && icb < 3) stageWin(icb + 1);
    }

    // window(icb+1) fully staged (both waves) before reading it; WAR on buf icb&1
    // certified for the stage at icb+2 by this same barrier.
    asm volatile("s_waitcnt vmcnt(0)" ::: "memory");
    __builtin_amdgcn_s_barrier();
    __builtin_amdgcn_sched_barrier(0);
  }

  // ---- epilogue: D row=(lane>>4)*4+reg (oc), col=lane&15 (pixel)
  #pragma unroll
  for (int j = 0; j < 7; ++j) {
    int pidx = rt * BNP + j * 16 + l15;           // pixel within image
    #pragma unroll
    for (int m = 0; m < 4; ++m) {
      int oc = ocb + wm * 64 + m * 16 + lh * 4;
      float* op = out + ((long)(n * OC + oc)) * NPIX + pidx;
      #pragma unroll
      for (int r = 0; r < 4; ++r)
        op[(long)r * NPIX] = acc[m][j][r];
    }
  }
}

// ---- fallback: naive direct conv fp32
__global__ __launch_bounds__(256) void conv_naive(const float* __restrict__ X,
                                                  const float* __restrict__ W,
                                                  float* __restrict__ out, int total) {
  int idx = blockIdx.x * 256 + threadIdx.x;
  if (idx >= total) return;
  int prow = idx % NPIX;
  int t    = idx / NPIX;
  int oc   = t % OC;
  int n    = t / OC;
  int oh = prow / WW, ow = prow % WW;
  float s = 0.f;
  for (int ic = 0; ic < IC; ++ic) {
    const float* xp = X + ((long)(n * IC + ic)) * NPIX;
    const float* wp = W + ((long)(oc * IC + ic)) * 9;
    #pragma unroll
    for (int kh = 0; kh < 3; ++kh) {
      int ih = oh + kh - 1;
      if (ih < 0 || ih >= HH) continue;
      #pragma unroll
      for (int kw = 0; kw < 3; ++kw) {
        int iw = ow + kw - 1;
        if (iw < 0 || iw >= WW) continue;
        s += xp[ih * WW + iw] * wp[kh * 3 + kw];
      }
    }
  }
  out[idx] = s;
}

extern "C" void kernel_launch(void* const* d_in, const int* in_sizes, int n_in,
                              void* d_out, int out_size, void* d_ws, size_t ws_size,
                              hipStream_t stream) {
  const float* X = (const float*)d_in[0];
  const float* W = (const float*)d_in[1];
  float* out = (float*)d_out;

  const size_t xt_elems = (size_t)NB * PS * IC;
  const size_t wb_elems = (size_t)9 * 16 * 256 * 8;   // 294,912
  const size_t need = (xt_elems + wb_elems) * sizeof(unsigned short);

  if (ws_size >= need) {
    unsigned short* Xt = (unsigned short*)d_ws;
    unsigned short* Wb = Xt + xt_elems;

    pad_x_nhwc<<<PADBLK + BORDBLK, 256, 0, stream>>>(X, Xt);
    int totW = (int)wb_elems;
    pack_w<<<(totW + 255) / 256, 256, 0, stream>>>(W, Wb, totW);
    conv_win<<<(GPIX / BNP) * (OC / 128), 128, 0, stream>>>(Xt, Wb, out);
  } else {
    int tot = NB * OC * NPIX;
    conv_naive<<<(tot + 255) / 256, 256, 0, stream>>>(X, W, out, tot);
  }
}